// Round 1
// 482.436 us; speedup vs baseline: 1.0139x; 1.0139x over previous
//
#include <hip/hip_runtime.h>
#include <math.h>

#define N_NODES 524288
#define BATCH   4096
#define HID     128
#define MAXL    1024   // max segment length safety bound (mean 128, sigma ~11)

typedef __attribute__((ext_vector_type(8))) short bf16x8;
typedef __attribute__((ext_vector_type(4))) float f32x4;

__device__ __forceinline__ unsigned short f2bf(float f) {
  unsigned int u = __float_as_uint(f);
  u = (u + 0x7FFFu + ((u >> 16) & 1u)) >> 16;   // RNE
  return (unsigned short)u;
}

// Fused: per-segment scores (bf16 MFMA MLP) -> softmax (LDS) -> weighted pooling.
// One 64-thread wave per segment; ball rows are HBM-read once (pooling pass
// re-reads them L1/L2-hot).
__global__ __launch_bounds__(64) void k_score_pool(
    const float* __restrict__ ball, const int* __restrict__ bb,
    const float* __restrict__ w1, const float* __restrict__ b1,
    const float* __restrict__ w2, const float* __restrict__ b2,
    float* __restrict__ pooled, int N)
{
  __shared__ float s_e[MAXL];
  const int lane = threadIdx.x;
  const int m16  = lane & 15;
  const int quad = lane >> 4;
  const int b    = blockIdx.x;

  // segment bounds: [lower_bound(b), lower_bound(b+1))  (bb sorted)
  int lo = 0, hi = N;
  while (lo < hi) { int mid = (lo + hi) >> 1; if (bb[mid] < b) lo = mid + 1; else hi = mid; }
  const int start = lo;
  hi = N;
  while (lo < hi) { int mid = (lo + hi) >> 1; if (bb[mid] < b + 1) lo = mid + 1; else hi = mid; }
  const int end = lo;
  int L = end - start;

  float4* outp = (float4*)(pooled + (size_t)b * HID);
  if (L <= 0) { if (lane < 32) outp[lane] = make_float4(0.f, 0.f, 0.f, 0.f); return; }
  if (L > MAXL) L = MAXL;   // statistically unreachable

  // ---- Phase A: scores = tanh(ball_seg @ W1 + b1) @ W2 + b2 -> LDS ----
  // W1 fragments: B[k][n], n = t*16+m16, k = s*32 + quad*8 + j  (L2-hot, 32 KB)
  bf16x8 fb[4][4];
  for (int t = 0; t < 4; ++t) {
    const int n = t * 16 + m16;
    for (int s = 0; s < 4; ++s) {
      const int k0 = s * 32 + quad * 8;
      bf16x8 v;
      #pragma unroll
      for (int j = 0; j < 8; ++j) v[j] = (short)f2bf(w1[(k0 + j) * 64 + n]);
      fb[t][s] = v;
    }
  }
  float b1v[4], w2v[4];
  #pragma unroll
  for (int t = 0; t < 4; ++t) { b1v[t] = b1[t*16 + m16]; w2v[t] = w2[t*16 + m16]; }
  const float b2v = b2[0];

  for (int t0 = 0; t0 < L; t0 += 16) {
    int row = start + t0 + m16;
    if (row > N - 1) row = N - 1;          // last-segment tile overhang guard
    const float* rowp = ball + (size_t)row * HID + quad * 8;
    f32x4 acc0 = {0.f,0.f,0.f,0.f}, acc1 = {0.f,0.f,0.f,0.f};
    f32x4 acc2 = {0.f,0.f,0.f,0.f}, acc3 = {0.f,0.f,0.f,0.f};
    #pragma unroll
    for (int s = 0; s < 4; ++s) {
      const float4* p = (const float4*)(rowp + s * 32);
      float4 x0 = p[0], x1 = p[1];
      bf16x8 fa;
      fa[0]=(short)f2bf(x0.x); fa[1]=(short)f2bf(x0.y);
      fa[2]=(short)f2bf(x0.z); fa[3]=(short)f2bf(x0.w);
      fa[4]=(short)f2bf(x1.x); fa[5]=(short)f2bf(x1.y);
      fa[6]=(short)f2bf(x1.z); fa[7]=(short)f2bf(x1.w);
      acc0 = __builtin_amdgcn_mfma_f32_16x16x32_bf16(fa, fb[0][s], acc0, 0,0,0);
      acc1 = __builtin_amdgcn_mfma_f32_16x16x32_bf16(fa, fb[1][s], acc1, 0,0,0);
      acc2 = __builtin_amdgcn_mfma_f32_16x16x32_bf16(fa, fb[2][s], acc2, 0,0,0);
      acc3 = __builtin_amdgcn_mfma_f32_16x16x32_bf16(fa, fb[3][s], acc3, 0,0,0);
    }
    // D layout: col(n within 16-tile)=m16, row(node within tile)=quad*4+r
    #pragma unroll
    for (int r = 0; r < 4; ++r) {
      float p = tanhf(acc0[r] + b1v[0]) * w2v[0]
              + tanhf(acc1[r] + b1v[1]) * w2v[1]
              + tanhf(acc2[r] + b1v[2]) * w2v[2]
              + tanhf(acc3[r] + b1v[3]) * w2v[3];
      p += __shfl_xor(p, 1); p += __shfl_xor(p, 2);
      p += __shfl_xor(p, 4); p += __shfl_xor(p, 8);
      const int idx = t0 + quad * 4 + r;
      if (m16 == 0 && idx < L) s_e[idx] = p + b2v;
    }
  }
  __syncthreads();

  // ---- Phase B: softmax over LDS scores (exp computed once per node) ----
  float m = -INFINITY;
  for (int i = lane; i < L; i += 64) m = fmaxf(m, s_e[i]);
  #pragma unroll
  for (int o = 32; o; o >>= 1) m = fmaxf(m, __shfl_xor(m, o));

  float d = 0.f;
  for (int i = lane; i < L; i += 64) { float e = expf(s_e[i] - m); s_e[i] = e; d += e; }
  __syncthreads();
  #pragma unroll
  for (int o = 32; o; o >>= 1) d += __shfl_xor(d, o);
  const float inv = 1.f / d;

  // ---- Phase C: pooled = (sum_i e_i * ball[i]) * inv  (rows L1/L2-hot) ----
  // 2 rows per load instruction: half-wave lh owns row i+lh, float4 col c4.
  const int lh = lane >> 5;
  const int c4 = lane & 31;
  float4 acc = {0.f, 0.f, 0.f, 0.f};
  int i = start;
  for (; i + 8 <= end; i += 8) {
    #pragma unroll
    for (int u = 0; u < 4; ++u) {
      const int row = i + 2 * u + lh;
      const float w = s_e[row - start];
      const float4 v = ((const float4*)(ball + (size_t)row * HID))[c4];
      acc.x = fmaf(w, v.x, acc.x);
      acc.y = fmaf(w, v.y, acc.y);
      acc.z = fmaf(w, v.z, acc.z);
      acc.w = fmaf(w, v.w, acc.w);
    }
  }
  for (; i + 2 <= end; i += 2) {
    const int row = i + lh;
    const float w = s_e[row - start];
    const float4 v = ((const float4*)(ball + (size_t)row * HID))[c4];
    acc.x = fmaf(w, v.x, acc.x);
    acc.y = fmaf(w, v.y, acc.y);
    acc.z = fmaf(w, v.z, acc.z);
    acc.w = fmaf(w, v.w, acc.w);
  }
  if (i < end && lh == 0) {
    const int row = i;
    const float w = s_e[row - start];
    const float4 v = ((const float4*)(ball + (size_t)row * HID))[c4];
    acc.x = fmaf(w, v.x, acc.x);
    acc.y = fmaf(w, v.y, acc.y);
    acc.z = fmaf(w, v.z, acc.z);
    acc.w = fmaf(w, v.w, acc.w);
  }
  acc.x += __shfl_xor(acc.x, 32);
  acc.y += __shfl_xor(acc.y, 32);
  acc.z += __shfl_xor(acc.z, 32);
  acc.w += __shfl_xor(acc.w, 32);
  if (lh == 0) {
    acc.x *= inv; acc.y *= inv; acc.z *= inv; acc.w *= inv;
    outp[c4] = acc;
  }
}

// K3: h = [query|pooled]@comb_w + comb_b -> LN -> GELU(exact) -> two heads.
// 8 rows per block, 128 threads (thread j owns output column j of h).
__global__ __launch_bounds__(128) void k_combine(
    const float* __restrict__ query, const float* __restrict__ pooled,
    const float* __restrict__ cw, const float* __restrict__ cb,
    const float* __restrict__ lg, const float* __restrict__ lb,
    const float* __restrict__ bw1, const float* __restrict__ bb1,
    const float* __restrict__ bw2, const float* __restrict__ bb2,
    const float* __restrict__ ww1, const float* __restrict__ wb1,
    const float* __restrict__ ww2, const float* __restrict__ wb2,
    float* __restrict__ out)
{
  __shared__ float in_lds[256][8];
  __shared__ float h_lds[128][8];
  __shared__ float part[2][2][8];
  const int tid  = threadIdx.x;
  const int row0 = blockIdx.x * 8;

  for (int idx = tid; idx < 2048; idx += 128) {
    const int k = idx >> 3, r = idx & 7;
    float v = (k < 128) ? query[(size_t)(row0 + r) * 128 + k]
                        : pooled[(size_t)(row0 + r) * 128 + (k - 128)];
    in_lds[k][r] = v;
  }
  __syncthreads();

  const int j = tid;
  float acc[8];
  const float cbj = cb[j];
  #pragma unroll
  for (int r = 0; r < 8; ++r) acc[r] = cbj;
  for (int k = 0; k < 256; ++k) {
    const float w = cw[k * 128 + j];
    #pragma unroll
    for (int r = 0; r < 8; ++r) acc[r] = fmaf(in_lds[k][r], w, acc[r]);
  }

  const int wv = tid >> 6, ln = tid & 63;
  #pragma unroll
  for (int r = 0; r < 8; ++r) {
    float v = acc[r], v2 = v * v;
    #pragma unroll
    for (int o = 32; o; o >>= 1) { v += __shfl_xor(v, o); v2 += __shfl_xor(v2, o); }
    if (ln == 0) { part[0][wv][r] = v; part[1][wv][r] = v2; }
  }
  __syncthreads();
  const float gj = lg[j], bj = lb[j];
  #pragma unroll
  for (int r = 0; r < 8; ++r) {
    const float S = part[0][0][r] + part[0][1][r];
    const float Q = part[1][0][r] + part[1][1][r];
    const float mean = S * (1.f / 128.f);
    const float var  = Q * (1.f / 128.f) - mean * mean;
    const float rs   = rsqrtf(var + 1e-5f);
    float x = (acc[r] - mean) * rs * gj + bj;
    x = 0.5f * x * (1.f + erff(x * 0.70710678118654752f));   // exact GELU
    h_lds[j][r] = x;
  }
  __syncthreads();

  // wave 0 -> boundary head, wave 1 -> wicket head; lane = hidden-out index (64)
  const float* W1 = wv ? ww1 : bw1;
  const float* B1 = wv ? wb1 : bb1;
  const float* W2 = wv ? ww2 : bw2;
  const float  B2 = wv ? wb2[0] : bb2[0];
  float t[8];
  const float b1l = B1[ln];
  #pragma unroll
  for (int r = 0; r < 8; ++r) t[r] = b1l;
  for (int k = 0; k < 128; ++k) {
    const float w = W1[k * 64 + ln];
    #pragma unroll
    for (int r = 0; r < 8; ++r) t[r] = fmaf(h_lds[k][r], w, t[r]);
  }
  const float w2l = W2[ln];
  #pragma unroll
  for (int r = 0; r < 8; ++r) {
    float o = fmaxf(t[r], 0.f) * w2l;
    #pragma unroll
    for (int m = 32; m; m >>= 1) o += __shfl_xor(o, m);
    if (ln == 0) out[wv * BATCH + row0 + r] = o + B2;
  }
}

extern "C" void kernel_launch(void* const* d_in, const int* in_sizes, int n_in,
                              void* d_out, int out_size, void* d_ws, size_t ws_size,
                              hipStream_t stream)
{
  const float* query = (const float*)d_in[0];
  const float* ball  = (const float*)d_in[1];
  const int*   bb    = (const int*)  d_in[2];
  const float* aw1   = (const float*)d_in[3];
  const float* ab1   = (const float*)d_in[4];
  const float* aw2   = (const float*)d_in[5];
  const float* ab2   = (const float*)d_in[6];
  const float* cw    = (const float*)d_in[7];
  const float* cb    = (const float*)d_in[8];
  const float* lg    = (const float*)d_in[9];
  const float* lbeta = (const float*)d_in[10];
  const float* bw1   = (const float*)d_in[11];
  const float* bb1   = (const float*)d_in[12];
  const float* bw2   = (const float*)d_in[13];
  const float* bb2   = (const float*)d_in[14];
  const float* ww1   = (const float*)d_in[15];
  const float* wb1   = (const float*)d_in[16];
  const float* ww2   = (const float*)d_in[17];
  const float* wb2   = (const float*)d_in[18];

  float* pooled = (float*)d_ws;              // B*H floats
  float* out    = (float*)d_out;

  k_score_pool<<<BATCH, 64, 0, stream>>>(ball, bb, aw1, ab1, aw2, ab2, pooled, N_NODES);
  k_combine<<<BATCH / 8, 128, 0, stream>>>(query, pooled, cw, cb, lg, lbeta,
                                           bw1, bb1, bw2, bb2, ww1, wb1, ww2, wb2, out);
}